// Round 6
// baseline (201.244 us; speedup 1.0000x reference)
//
#include <hip/hip_runtime.h>
#include <math.h>

typedef short short8 __attribute__((ext_vector_type(8)));
typedef float f32x4 __attribute__((ext_vector_type(4)));

typedef __attribute__((address_space(1))) const void* as1p;
typedef __attribute__((address_space(3))) void* as3p;

__device__ __forceinline__ unsigned short f2bf(float f) {
    unsigned int u = __float_as_uint(f);
    u += 0x7fffu + ((u >> 16) & 1u);          // RNE; inputs finite
    return (unsigned short)(u >> 16);
}
__device__ __forceinline__ float bf2f(unsigned int bits) {
    return __uint_as_float(bits << 16);
}

// ---------------------------------------------------------------------------
// fp32 -> bf16 conversion of x, W_qkv, W_o in one launch (4 elems/thread)
// ---------------------------------------------------------------------------
__global__ void cvt_all_bf16(const float* __restrict__ x,
                             const float* __restrict__ wqkv,
                             const float* __restrict__ wo,
                             unsigned short* __restrict__ xb,
                             unsigned short* __restrict__ wqkvb,
                             unsigned short* __restrict__ wob) {
    int i = blockIdx.x * blockDim.x + threadIdx.x;   // [0, 2097152)
    const float* src;
    unsigned short* dst;
    int off;
    if (i < 1048576)       { src = x;    dst = xb;    off = i; }
    else if (i < 1835008)  { src = wqkv; dst = wqkvb; off = i - 1048576; }
    else                   { src = wo;   dst = wob;   off = i - 1835008; }
    float4 v = ((const float4*)src)[off];
    ushort4 o = make_ushort4(f2bf(v.x), f2bf(v.y), f2bf(v.z), f2bf(v.w));
    ((ushort4*)dst)[off] = o;
}

// ---------------------------------------------------------------------------
// MFMA NT GEMM: C[m,n] = sum_k A[m,k]*B[n,k]. Block tile BM x 128 (BM=RF*32),
// BK=32, 4 waves (2x2), global_load_lds width-16 staging (m97 structure).
// XCD-swizzled flat grid: xcd = L%8 owns NTX consecutive n-tiles (its B panel
// stays L2-resident: qkv 786 KB, out-proj 256 KB < 4 MiB); m sweeps within.
// DO_ROPE: fused RoPE on the fp32 accumulator before the bf16 store (q/k
// sections only; q additionally scaled by 1/8*log2e for the flash kernel).
// ---------------------------------------------------------------------------
template <int RF, int NTX, bool BF16_OUT, bool DO_ROPE>
__global__ __launch_bounds__(256) void gemm_nt_mfma(
    const unsigned short* __restrict__ A, const unsigned short* __restrict__ B,
    void* __restrict__ Cv, const int* __restrict__ pos, int N, int K) {
    constexpr int BM = RF * 32;
    __shared__ unsigned short As[BM * 32];
    __shared__ unsigned short Bs[128 * 32];
    const int tid = threadIdx.x;
    const int wave = tid >> 6, lane = tid & 63;
    const int L = blockIdx.x;
    const int xcd = L & 7, idx = L >> 3;
    const int nt_ = xcd * NTX + idx % NTX;
    const int mt  = idx / NTX;
    const int m0 = mt * BM, n0 = nt_ << 7;
    const int wr = ((wave >> 1) & 1) * (RF * 16);
    const int wc = (wave & 1) << 6;

    const int r0 = tid >> 2, ko = (tid & 3) << 3;
    const unsigned short* Ap0 = A + (size_t)(m0 + r0) * K + ko;
    const unsigned short* Ap1 = A + (size_t)(m0 + (RF == 4 ? 64 : 0) + r0) * K + ko;
    const unsigned short* Bp0 = B + (size_t)(n0 + r0) * K + ko;
    const unsigned short* Bp1 = B + (size_t)(n0 + 64 + r0) * K + ko;

    f32x4 acc[RF][4] = {};
    const int lro = lane & 15, g8 = (lane >> 4) << 3;

    for (int k0 = 0; k0 < K; k0 += 32) {
        __syncthreads();
        __builtin_amdgcn_global_load_lds((as1p)(Ap0 + k0), (as3p)(As + tid * 8), 16, 0, 0);
        if constexpr (RF == 4)
            __builtin_amdgcn_global_load_lds((as1p)(Ap1 + k0), (as3p)(As + (256 + tid) * 8), 16, 0, 0);
        __builtin_amdgcn_global_load_lds((as1p)(Bp0 + k0), (as3p)(Bs + tid * 8), 16, 0, 0);
        __builtin_amdgcn_global_load_lds((as1p)(Bp1 + k0), (as3p)(Bs + (256 + tid) * 8), 16, 0, 0);
        __syncthreads();

        short8 af[RF], bfr[4];
        #pragma unroll
        for (int i = 0; i < RF; i++) af[i] = *(const short8*)&As[(wr + i * 16 + lro) * 32 + g8];
        #pragma unroll
        for (int j = 0; j < 4; j++) bfr[j] = *(const short8*)&Bs[(wc + j * 16 + lro) * 32 + g8];
        #pragma unroll
        for (int i = 0; i < RF; i++)
            #pragma unroll
            for (int j = 0; j < 4; j++)
                acc[i][j] = __builtin_amdgcn_mfma_f32_16x16x32_bf16(af[i], bfr[j], acc[i][j], 0, 0, 0);
    }

    const int row_b = m0 + wr + ((lane >> 4) << 2);
    const int col_b = n0 + wc + lro;

    if constexpr (DO_ROPE) {
        const int sec = (n0 + wc) >> 10;           // 0=q, 1=k, 2=v
        if (sec < 2) {
            const float qs = (sec == 0) ? 0.18033688011112042f : 1.0f;  // 1/8*log2e
            const float sgn = (lane & 1) ? 1.0f : -1.0f;
            float ps[RF * 4];
            #pragma unroll
            for (int i = 0; i < RF; i++)
                #pragma unroll
                for (int r = 0; r < 4; r++)
                    ps[i * 4 + r] = (float)pos[(row_b + i * 16 + r) & 2047];
            #pragma unroll
            for (int j = 0; j < 4; j++) {
                // inv_freq / (2*pi):  10000^(-fi/32) * 0.159155,  fi = lro/2 + 8j
                float invf_rev = exp2f(-(float)((lro >> 1) + 8 * j) * 0.41524101186092029f)
                                 * 0.15915494309189535f;
                #pragma unroll
                for (int i = 0; i < RF; i++)
                    #pragma unroll
                    for (int r = 0; r < 4; r++) {
                        float rev = ps[i * 4 + r] * invf_rev;
                        rev -= floorf(rev);
                        float c = __builtin_amdgcn_cosf(rev) * qs;
                        float s = __builtin_amdgcn_sinf(rev) * (qs * sgn);
                        float mine = acc[i][j][r];
                        float partner = __shfl_xor(mine, 1, 64);
                        acc[i][j][r] = mine * c + partner * s;
                    }
            }
        }
    }

    #pragma unroll
    for (int i = 0; i < RF; i++)
        #pragma unroll
        for (int j = 0; j < 4; j++)
            #pragma unroll
            for (int r = 0; r < 4; r++) {
                size_t idx2 = (size_t)(row_b + i * 16 + r) * N + (col_b + j * 16);
                if constexpr (BF16_OUT) ((unsigned short*)Cv)[idx2] = f2bf(acc[i][j][r]);
                else ((float*)Cv)[idx2] = acc[i][j][r];
            }
}

// ---------------------------------------------------------------------------
// MFMA causal flash attention. 1024 blocks, one 64-row q-tile each, LPT order
// (qt descending per XCD group) for tail-fill; XCD-swizzled so all 32 q-tile
// blocks of one (b,h) share one XCD (K/V L2-resident — r5: FETCH 122->12 MB).
// Q frags loaded DIRECTLY global->registers (A-frag layout, no LDS buffer):
// LDS 45 KB -> 3 blocks/CU (was grid-limited to 2).
// Softmax: scores pre-scaled (rope folded 1/8*log2e into q), no running max,
// denominator reduced once in the epilogue. Per iter ONE barrier; K(kt+1)
// async global_load_lds; V(kt+1) register-prefetch + transpose at iter bottom.
// K LDS 16B-chunk XOR swizzle; V quad-swizzled; P stride 80.
// ---------------------------------------------------------------------------
__global__ __launch_bounds__(256) void flash_attn_mfma(
    const unsigned short* __restrict__ qkv, unsigned short* __restrict__ Ows) {
    const int S = 2048, D3 = 3072;
    const int L = blockIdx.x;
    const int xcd = L & 7, t = L >> 3;
    const int g2 = xcd + ((t >> 5) << 3);      // (b,h) group, constant per XCD
    const int h = g2 & 15, b = g2 >> 4;
    const int qt = 31 - (t & 31);              // LPT: big tiles dispatched first
    const int q0 = qt << 6, nkt = qt + 1;
    const int tid = threadIdx.x, wave = tid >> 6, lane = tid & 63;
    const int lro = lane & 15, grp = lane >> 4;

    __shared__ __align__(16) unsigned short Ks[2][64 * 64];
    __shared__ __align__(16) unsigned int   Vp[2][64 * 36];
    __shared__ __align__(16) unsigned short Ps[64 * 80];

    // staging geometry (K): slot s -> row s>>3, swizzled source chunk
    const int sr = tid >> 3;
    const int sc = ((tid & 7) ^ (sr & 7)) << 3;
    // V transpose geometry
    const int kp = tid >> 3, vo = (tid & 7) << 3;
    const int vka = (kp >> 1) + ((kp & 1) << 5);
    const int vcol = (((kp >> 2) ^ (tid & 7)) << 2) | (kp & 3);

    // frag LDS offsets
    const int cq = grp ^ (lro & 7);
    int kof0[4], kof1[4], vbse[4], vq[4];
    #pragma unroll
    for (int nt = 0; nt < 4; nt++) {
        int R = nt * 16 + lro;
        kof0[nt] = R * 64 + cq * 8;
        kof1[nt] = R * 64 + (cq ^ 4) * 8;
        vbse[nt] = R * 36;
        vq[nt] = (grp ^ (R >> 3)) << 2;
    }
    const int apo = (wave * 16 + lro) * 80 + grp * 8;
    const int prow = wave * 16 + grp * 4;

    const unsigned short* kbg = qkv + (size_t)(b * S) * D3 + 1024 + h * 64;
    const unsigned short* vbg = qkv + (size_t)(b * S) * D3 + 2048 + h * 64;

    // Q frags direct from global (A-layout: row = wave*16+lro, k = grp*8(+32))
    const unsigned short* qrow =
        qkv + (size_t)(b * S + q0 + wave * 16 + lro) * D3 + h * 64 + grp * 8;
    short8 aq0 = *(const short8*)qrow;
    short8 aq1 = *(const short8*)(qrow + 32);

    // prime tile 0: K async, V reg->transpose
    __builtin_amdgcn_global_load_lds((as1p)(kbg + (size_t)sr * D3 + sc),
                                     (as3p)&Ks[0][tid * 8], 16, 0, 0);
    __builtin_amdgcn_global_load_lds((as1p)(kbg + (size_t)(sr + 32) * D3 + sc),
                                     (as3p)&Ks[0][(tid + 256) * 8], 16, 0, 0);
    {
        const unsigned short* vs = vbg + (size_t)vka * D3 + vo;
        uint4 va = *(const uint4*)vs;
        uint4 vb = *(const uint4*)(vs + (size_t)16 * D3);
        const unsigned short* pa = (const unsigned short*)&va;
        const unsigned short* pb = (const unsigned short*)&vb;
        #pragma unroll
        for (int j = 0; j < 8; j++)
            Vp[0][(vo + j) * 36 + vcol] = (unsigned)pa[j] | ((unsigned)pb[j] << 16);
    }
    __syncthreads();                       // K0 drained, V0 visible

    f32x4 acc_o[4] = {};
    float lsum[4] = {0.f, 0.f, 0.f, 0.f};

    for (int kt = 0; kt < nkt; kt++) {
        const int cur = kt & 1, nxt = cur ^ 1;
        const bool pf = (kt + 1 < nkt);
        uint4 va, vb;
        if (pf) {                          // prefetch kt+1 (overlaps compute)
            const unsigned short* kb1 = kbg + (size_t)((kt + 1) * 64) * D3;
            __builtin_amdgcn_global_load_lds((as1p)(kb1 + (size_t)sr * D3 + sc),
                                             (as3p)&Ks[nxt][tid * 8], 16, 0, 0);
            __builtin_amdgcn_global_load_lds((as1p)(kb1 + (size_t)(sr + 32) * D3 + sc),
                                             (as3p)&Ks[nxt][(tid + 256) * 8], 16, 0, 0);
            const unsigned short* vs = vbg + (size_t)((kt + 1) * 64 + vka) * D3 + vo;
            va = *(const uint4*)vs;
            vb = *(const uint4*)(vs + (size_t)16 * D3);
        }

        // S = Q K^T  (pre-scaled so p = exp2(s))
        f32x4 s[4] = {};
        #pragma unroll
        for (int nt = 0; nt < 4; nt++) {
            short8 bk0 = *(const short8*)&Ks[cur][kof0[nt]];
            short8 bk1 = *(const short8*)&Ks[cur][kof1[nt]];
            s[nt] = __builtin_amdgcn_mfma_f32_16x16x32_bf16(aq0, bk0, s[nt], 0, 0, 0);
            s[nt] = __builtin_amdgcn_mfma_f32_16x16x32_bf16(aq1, bk1, s[nt], 0, 0, 0);
        }

        const bool diag = (kt == nkt - 1);
        #pragma unroll
        for (int r = 0; r < 4; r++) {
            float v0 = s[0][r], v1 = s[1][r], v2 = s[2][r], v3 = s[3][r];
            if (diag) {
                int rowl = prow + r;
                if (lro > rowl) v0 = -1e30f;
                if (16 + lro > rowl) v1 = -1e30f;
                if (32 + lro > rowl) v2 = -1e30f;
                if (48 + lro > rowl) v3 = -1e30f;
            }
            float p0 = __builtin_amdgcn_exp2f(v0);
            float p1 = __builtin_amdgcn_exp2f(v1);
            float p2 = __builtin_amdgcn_exp2f(v2);
            float p3 = __builtin_amdgcn_exp2f(v3);
            lsum[r] += (p0 + p1) + (p2 + p3);
            // cheap (round-half-up) bf16 pack
            unsigned u0 = __float_as_uint(p0) + 0x8000u;
            unsigned u1 = __float_as_uint(p1) + 0x8000u;
            unsigned u2 = __float_as_uint(p2) + 0x8000u;
            unsigned u3 = __float_as_uint(p3) + 0x8000u;
            uint2 w = make_uint2((u0 >> 16) | (u1 & 0xffff0000u),
                                 (u2 >> 16) | (u3 & 0xffff0000u));
            *(uint2*)&Ps[(prow + r) * 80 + lro * 4] = w;
        }

        // O += P V  (same-wave in-order LDS RAW on Ps)
        short8 ap0 = *(const short8*)&Ps[apo];
        short8 ap1 = *(const short8*)&Ps[apo + 32];
        #pragma unroll
        for (int nt = 0; nt < 4; nt++) {
            short8 bv0 = *(const short8*)&Vp[cur][vbse[nt] + vq[nt]];
            short8 bv1 = *(const short8*)&Vp[cur][vbse[nt] + (vq[nt] ^ 16)];
            acc_o[nt] = __builtin_amdgcn_mfma_f32_16x16x32_bf16(ap0, bv0, acc_o[nt], 0, 0, 0);
            acc_o[nt] = __builtin_amdgcn_mfma_f32_16x16x32_bf16(ap1, bv1, acc_o[nt], 0, 0, 0);
        }

        if (pf) {                          // transpose-write V(kt+1)
            const unsigned short* pa = (const unsigned short*)&va;
            const unsigned short* pb = (const unsigned short*)&vb;
            #pragma unroll
            for (int j = 0; j < 8; j++)
                Vp[nxt][(vo + j) * 36 + vcol] = (unsigned)pa[j] | ((unsigned)pb[j] << 16);
        }
        __syncthreads();                   // drains async K(kt+1); Vp[nxt] visible
    }

    // epilogue: reduce l across the 16 lanes holding this row, normalize
    #pragma unroll
    for (int r = 0; r < 4; r++) {
        float rsum = lsum[r];
        #pragma unroll
        for (int off = 1; off < 16; off <<= 1)
            rsum += __shfl_xor(rsum, off, 16);
        float inv = 1.0f / rsum;
        int row = q0 + prow + r;
        #pragma unroll
        for (int nt = 0; nt < 4; nt++)
            Ows[(size_t)(b * S + row) * 1024 + h * 64 + nt * 16 + lro] =
                f2bf(acc_o[nt][r] * inv);
    }
}

// ---------------------------------------------------------------------------
extern "C" void kernel_launch(void* const* d_in, const int* in_sizes, int n_in,
                              void* d_out, int out_size, void* d_ws, size_t ws_size,
                              hipStream_t stream) {
    const float* x    = (const float*)d_in[0];   // (2, 2048, 1024)
    const int*   pos  = (const int*)d_in[1];     // (2048,)
    const float* Wqkv = (const float*)d_in[2];   // (3072, 1024)
    const float* Wo   = (const float*)d_in[3];   // (1024, 1024)
    float* out = (float*)d_out;                  // (2, 2048, 1024) fp32

    unsigned short* xb    = (unsigned short*)d_ws;            // 4096*1024
    unsigned short* Wqkvb = xb + (size_t)4096 * 1024;         // 3072*1024
    unsigned short* Wob   = Wqkvb + (size_t)3072 * 1024;      // 1024*1024
    unsigned short* qkvb  = Wob + (size_t)1024 * 1024;        // 4096*3072
    unsigned short* Owsb  = qkvb + (size_t)4096 * 3072;       // 4096*1024

    // 0) fp32 -> bf16 (single launch)
    cvt_all_bf16<<<8192, 256, 0, stream>>>(x, Wqkv, Wo, xb, Wqkvb, Wob);

    // 1) QKV projection (M=4096, N=3072, K=1024) + fused RoPE, XCD-swizzled
    gemm_nt_mfma<4, 3, true, true><<<768, 256, 0, stream>>>(
        xb, Wqkvb, qkvb, pos, 3072, 1024);

    // 2) causal flash attention (1024 single-tile blocks, LPT, XCD-swizzled)
    flash_attn_mfma<<<1024, 256, 0, stream>>>(qkvb, Owsb);

    // 3) output projection (M=4096, N=1024, K=1024), BM=64, XCD-swizzled
    gemm_nt_mfma<2, 1, false, false><<<512, 256, 0, stream>>>(
        Owsb, Wob, out, nullptr, 1024, 1024);
}

// Round 7
// 195.985 us; speedup vs baseline: 1.0268x; 1.0268x over previous
//
#include <hip/hip_runtime.h>
#include <math.h>

typedef short short8 __attribute__((ext_vector_type(8)));
typedef float f32x4 __attribute__((ext_vector_type(4)));

typedef __attribute__((address_space(1))) const void* as1p;
typedef __attribute__((address_space(3))) void* as3p;

__device__ __forceinline__ unsigned short f2bf(float f) {
    unsigned int u = __float_as_uint(f);
    u += 0x7fffu + ((u >> 16) & 1u);          // RNE; inputs finite
    return (unsigned short)(u >> 16);
}
__device__ __forceinline__ float bf2f(unsigned int bits) {
    return __uint_as_float(bits << 16);
}

// ---------------------------------------------------------------------------
// fp32 -> bf16 conversion of x, W_qkv, W_o in one launch (4 elems/thread)
// ---------------------------------------------------------------------------
__global__ void cvt_all_bf16(const float* __restrict__ x,
                             const float* __restrict__ wqkv,
                             const float* __restrict__ wo,
                             unsigned short* __restrict__ xb,
                             unsigned short* __restrict__ wqkvb,
                             unsigned short* __restrict__ wob) {
    int i = blockIdx.x * blockDim.x + threadIdx.x;   // [0, 2097152)
    const float* src;
    unsigned short* dst;
    int off;
    if (i < 1048576)       { src = x;    dst = xb;    off = i; }
    else if (i < 1835008)  { src = wqkv; dst = wqkvb; off = i - 1048576; }
    else                   { src = wo;   dst = wob;   off = i - 1835008; }
    float4 v = ((const float4*)src)[off];
    ushort4 o = make_ushort4(f2bf(v.x), f2bf(v.y), f2bf(v.z), f2bf(v.w));
    ((ushort4*)dst)[off] = o;
}

// ---------------------------------------------------------------------------
// MFMA NT GEMM, DOUBLE-BUFFERED: C[m,n] = sum_k A[m,k]*B[n,k].
// Block tile BM x 128 (BM=RF*32), BK=32, 4 waves (2x2).
// K-loop is the flash-proven one-barrier pipeline: prefetch k+1 via async
// global_load_lds at the TOP of iter k, compute from the other buffer, and
// let the bottom-of-iter barrier (vmcnt drain) complete the prefetch —
// memory latency covered by the MFMA phase (r6 theory: the old 2-barrier
// loop exposed full L2/HBM latency every iteration).
// XCD-swizzled flat grid: xcd = L%8 owns NTX consecutive n-tiles.
// DO_ROPE: fused RoPE on the fp32 accumulator before the bf16 store.
// ---------------------------------------------------------------------------
template <int RF, int NTX, bool BF16_OUT, bool DO_ROPE>
__global__ __launch_bounds__(256) void gemm_nt_mfma(
    const unsigned short* __restrict__ A, const unsigned short* __restrict__ B,
    void* __restrict__ Cv, const int* __restrict__ pos, int N, int K) {
    constexpr int BM = RF * 32;
    __shared__ unsigned short As[2][BM * 32];
    __shared__ unsigned short Bs[2][128 * 32];
    const int tid = threadIdx.x;
    const int wave = tid >> 6, lane = tid & 63;
    const int L = blockIdx.x;
    const int xcd = L & 7, idx = L >> 3;
    const int nt_ = xcd * NTX + idx % NTX;
    const int mt  = idx / NTX;
    const int m0 = mt * BM, n0 = nt_ << 7;
    const int wr = ((wave >> 1) & 1) * (RF * 16);
    const int wc = (wave & 1) << 6;

    const int r0 = tid >> 2, ko = (tid & 3) << 3;
    const unsigned short* Ap0 = A + (size_t)(m0 + r0) * K + ko;
    const unsigned short* Ap1 = A + (size_t)(m0 + (RF == 4 ? 64 : 0) + r0) * K + ko;
    const unsigned short* Bp0 = B + (size_t)(n0 + r0) * K + ko;
    const unsigned short* Bp1 = B + (size_t)(n0 + 64 + r0) * K + ko;

    f32x4 acc[RF][4] = {};
    const int lro = lane & 15, g8 = (lane >> 4) << 3;

    // prime buffer 0
    __builtin_amdgcn_global_load_lds((as1p)Ap0, (as3p)(As[0] + tid * 8), 16, 0, 0);
    if constexpr (RF == 4)
        __builtin_amdgcn_global_load_lds((as1p)Ap1, (as3p)(As[0] + (256 + tid) * 8), 16, 0, 0);
    __builtin_amdgcn_global_load_lds((as1p)Bp0, (as3p)(Bs[0] + tid * 8), 16, 0, 0);
    __builtin_amdgcn_global_load_lds((as1p)Bp1, (as3p)(Bs[0] + (256 + tid) * 8), 16, 0, 0);
    __syncthreads();                           // buffer 0 ready

    for (int k0 = 0; k0 < K; k0 += 32) {
        const int cur = (k0 >> 5) & 1, nxt = cur ^ 1;
        if (k0 + 32 < K) {                     // prefetch k+1 (in flight across compute)
            __builtin_amdgcn_global_load_lds((as1p)(Ap0 + k0 + 32),
                                             (as3p)(As[nxt] + tid * 8), 16, 0, 0);
            if constexpr (RF == 4)
                __builtin_amdgcn_global_load_lds((as1p)(Ap1 + k0 + 32),
                                                 (as3p)(As[nxt] + (256 + tid) * 8), 16, 0, 0);
            __builtin_amdgcn_global_load_lds((as1p)(Bp0 + k0 + 32),
                                             (as3p)(Bs[nxt] + tid * 8), 16, 0, 0);
            __builtin_amdgcn_global_load_lds((as1p)(Bp1 + k0 + 32),
                                             (as3p)(Bs[nxt] + (256 + tid) * 8), 16, 0, 0);
        }

        short8 af[RF], bfr[4];
        #pragma unroll
        for (int i = 0; i < RF; i++) af[i] = *(const short8*)&As[cur][(wr + i * 16 + lro) * 32 + g8];
        #pragma unroll
        for (int j = 0; j < 4; j++) bfr[j] = *(const short8*)&Bs[cur][(wc + j * 16 + lro) * 32 + g8];
        #pragma unroll
        for (int i = 0; i < RF; i++)
            #pragma unroll
            for (int j = 0; j < 4; j++)
                acc[i][j] = __builtin_amdgcn_mfma_f32_16x16x32_bf16(af[i], bfr[j], acc[i][j], 0, 0, 0);
        __syncthreads();                       // drains prefetch; cur free for reuse
    }

    const int row_b = m0 + wr + ((lane >> 4) << 2);
    const int col_b = n0 + wc + lro;

    if constexpr (DO_ROPE) {
        const int sec = (n0 + wc) >> 10;           // 0=q, 1=k, 2=v
        if (sec < 2) {
            const float qs = (sec == 0) ? 0.18033688011112042f : 1.0f;  // 1/8*log2e
            const float sgn = (lane & 1) ? 1.0f : -1.0f;
            float ps[RF * 4];
            #pragma unroll
            for (int i = 0; i < RF; i++)
                #pragma unroll
                for (int r = 0; r < 4; r++)
                    ps[i * 4 + r] = (float)pos[(row_b + i * 16 + r) & 2047];
            #pragma unroll
            for (int j = 0; j < 4; j++) {
                // inv_freq / (2*pi):  10000^(-fi/32) * 0.159155,  fi = lro/2 + 8j
                float invf_rev = exp2f(-(float)((lro >> 1) + 8 * j) * 0.41524101186092029f)
                                 * 0.15915494309189535f;
                #pragma unroll
                for (int i = 0; i < RF; i++)
                    #pragma unroll
                    for (int r = 0; r < 4; r++) {
                        float rev = ps[i * 4 + r] * invf_rev;
                        rev -= floorf(rev);
                        float c = __builtin_amdgcn_cosf(rev) * qs;
                        float s = __builtin_amdgcn_sinf(rev) * (qs * sgn);
                        float mine = acc[i][j][r];
                        float partner = __shfl_xor(mine, 1, 64);
                        acc[i][j][r] = mine * c + partner * s;
                    }
            }
        }
    }

    #pragma unroll
    for (int i = 0; i < RF; i++)
        #pragma unroll
        for (int j = 0; j < 4; j++)
            #pragma unroll
            for (int r = 0; r < 4; r++) {
                size_t idx2 = (size_t)(row_b + i * 16 + r) * N + (col_b + j * 16);
                if constexpr (BF16_OUT) ((unsigned short*)Cv)[idx2] = f2bf(acc[i][j][r]);
                else ((float*)Cv)[idx2] = acc[i][j][r];
            }
}

// ---------------------------------------------------------------------------
// MFMA causal flash attention — r5 paired-balanced structure (the r6 LPT
// un-pairing regressed: 512 blocks x exactly 33 iters beats 1024 ragged).
// Block pp handles q-tiles pp and 31-pp; XCD-swizzled so all 16 blocks of a
// (b,h) share one XCD (K/V L2-resident, FETCH 122->12 MB). Q frags loaded
// directly global->registers (r6-proven; no Qs LDS buffer).
// Softmax: scores pre-scaled (rope folded 1/8*log2e into q), no running max,
// denominator reduced once per phase. Per iter ONE barrier; K(kt+1) async
// global_load_lds; V(kt+1) register-prefetch + transpose at iter bottom.
// K LDS 16B-chunk XOR swizzle; V quad-swizzled; P stride 80.
// ---------------------------------------------------------------------------
__global__ __launch_bounds__(256) void flash_attn_mfma(
    const unsigned short* __restrict__ qkv, unsigned short* __restrict__ Ows) {
    const int S = 2048, D3 = 3072;
    const int L = blockIdx.x + (blockIdx.y << 4) + (blockIdx.z << 8);
    const int xcd = L & 7, t = L >> 3;
    const int pp = t & 15;
    const int g2 = xcd + ((t >> 4) << 3);      // (b,h) group, constant per XCD
    const int h = g2 & 15, b = g2 >> 4;
    const int tid = threadIdx.x, wave = tid >> 6, lane = tid & 63;
    const int lro = lane & 15, grp = lane >> 4;

    __shared__ __align__(16) unsigned short Ks[2][64 * 64];
    __shared__ __align__(16) unsigned int   Vp[2][64 * 36];
    __shared__ __align__(16) unsigned short Ps[64 * 80];

    // staging geometry (K): slot s -> row s>>3, swizzled source chunk
    const int sr = tid >> 3;
    const int sc = ((tid & 7) ^ (sr & 7)) << 3;
    // V transpose geometry
    const int kp = tid >> 3, vo = (tid & 7) << 3;
    const int vka = (kp >> 1) + ((kp & 1) << 5);
    const int vcol = (((kp >> 2) ^ (tid & 7)) << 2) | (kp & 3);

    // frag LDS offsets
    const int cq = grp ^ (lro & 7);
    int kof0[4], kof1[4], vbse[4], vq[4];
    #pragma unroll
    for (int nt = 0; nt < 4; nt++) {
        int R = nt * 16 + lro;
        kof0[nt] = R * 64 + cq * 8;
        kof1[nt] = R * 64 + (cq ^ 4) * 8;
        vbse[nt] = R * 36;
        vq[nt] = (grp ^ (R >> 3)) << 2;
    }
    const int apo = (wave * 16 + lro) * 80 + grp * 8;
    const int prow = wave * 16 + grp * 4;

    const unsigned short* kbg = qkv + (size_t)(b * S) * D3 + 1024 + h * 64;
    const unsigned short* vbg = qkv + (size_t)(b * S) * D3 + 2048 + h * 64;

    for (int ph = 0; ph < 2; ph++) {
        const int qt = ph ? 31 - pp : pp;
        const int q0 = qt << 6;
        const int nkt = qt + 1;

        __syncthreads();                       // prior phase fully done with LDS
        // Q frags direct from global (A-layout: row = wave*16+lro, k = grp*8(+32))
        const unsigned short* qrow =
            qkv + (size_t)(b * S + q0 + wave * 16 + lro) * D3 + h * 64 + grp * 8;
        short8 aq0 = *(const short8*)qrow;
        short8 aq1 = *(const short8*)(qrow + 32);

        // prime tile 0: K async, V reg->transpose
        __builtin_amdgcn_global_load_lds((as1p)(kbg + (size_t)sr * D3 + sc),
                                         (as3p)&Ks[0][tid * 8], 16, 0, 0);
        __builtin_amdgcn_global_load_lds((as1p)(kbg + (size_t)(sr + 32) * D3 + sc),
                                         (as3p)&Ks[0][(tid + 256) * 8], 16, 0, 0);
        {
            const unsigned short* vs = vbg + (size_t)vka * D3 + vo;
            uint4 va = *(const uint4*)vs;
            uint4 vb = *(const uint4*)(vs + (size_t)16 * D3);
            const unsigned short* pa = (const unsigned short*)&va;
            const unsigned short* pb = (const unsigned short*)&vb;
            #pragma unroll
            for (int j = 0; j < 8; j++)
                Vp[0][(vo + j) * 36 + vcol] = (unsigned)pa[j] | ((unsigned)pb[j] << 16);
        }
        __syncthreads();                       // K0 drained, V0 visible

        f32x4 acc_o[4] = {};
        float lsum[4] = {0.f, 0.f, 0.f, 0.f};

        for (int kt = 0; kt < nkt; kt++) {
            const int cur = kt & 1, nxt = cur ^ 1;
            const bool pf = (kt + 1 < nkt);
            uint4 va, vb;
            if (pf) {                          // prefetch kt+1 (overlaps compute)
                const unsigned short* kb1 = kbg + (size_t)((kt + 1) * 64) * D3;
                __builtin_amdgcn_global_load_lds((as1p)(kb1 + (size_t)sr * D3 + sc),
                                                 (as3p)&Ks[nxt][tid * 8], 16, 0, 0);
                __builtin_amdgcn_global_load_lds((as1p)(kb1 + (size_t)(sr + 32) * D3 + sc),
                                                 (as3p)&Ks[nxt][(tid + 256) * 8], 16, 0, 0);
                const unsigned short* vs = vbg + (size_t)((kt + 1) * 64 + vka) * D3 + vo;
                va = *(const uint4*)vs;
                vb = *(const uint4*)(vs + (size_t)16 * D3);
            }

            // S = Q K^T  (pre-scaled so p = exp2(s))
            f32x4 s[4] = {};
            #pragma unroll
            for (int nt = 0; nt < 4; nt++) {
                short8 bk0 = *(const short8*)&Ks[cur][kof0[nt]];
                short8 bk1 = *(const short8*)&Ks[cur][kof1[nt]];
                s[nt] = __builtin_amdgcn_mfma_f32_16x16x32_bf16(aq0, bk0, s[nt], 0, 0, 0);
                s[nt] = __builtin_amdgcn_mfma_f32_16x16x32_bf16(aq1, bk1, s[nt], 0, 0, 0);
            }

            const bool diag = (kt == nkt - 1);
            #pragma unroll
            for (int r = 0; r < 4; r++) {
                float v0 = s[0][r], v1 = s[1][r], v2 = s[2][r], v3 = s[3][r];
                if (diag) {
                    int rowl = prow + r;
                    if (lro > rowl) v0 = -1e30f;
                    if (16 + lro > rowl) v1 = -1e30f;
                    if (32 + lro > rowl) v2 = -1e30f;
                    if (48 + lro > rowl) v3 = -1e30f;
                }
                float p0 = __builtin_amdgcn_exp2f(v0);
                float p1 = __builtin_amdgcn_exp2f(v1);
                float p2 = __builtin_amdgcn_exp2f(v2);
                float p3 = __builtin_amdgcn_exp2f(v3);
                lsum[r] += (p0 + p1) + (p2 + p3);
                // cheap (round-half-up) bf16 pack
                unsigned u0 = __float_as_uint(p0) + 0x8000u;
                unsigned u1 = __float_as_uint(p1) + 0x8000u;
                unsigned u2 = __float_as_uint(p2) + 0x8000u;
                unsigned u3 = __float_as_uint(p3) + 0x8000u;
                uint2 w = make_uint2((u0 >> 16) | (u1 & 0xffff0000u),
                                     (u2 >> 16) | (u3 & 0xffff0000u));
                *(uint2*)&Ps[(prow + r) * 80 + lro * 4] = w;
            }

            // O += P V  (same-wave in-order LDS RAW on Ps)
            short8 ap0 = *(const short8*)&Ps[apo];
            short8 ap1 = *(const short8*)&Ps[apo + 32];
            #pragma unroll
            for (int nt = 0; nt < 4; nt++) {
                short8 bv0 = *(const short8*)&Vp[cur][vbse[nt] + vq[nt]];
                short8 bv1 = *(const short8*)&Vp[cur][vbse[nt] + (vq[nt] ^ 16)];
                acc_o[nt] = __builtin_amdgcn_mfma_f32_16x16x32_bf16(ap0, bv0, acc_o[nt], 0, 0, 0);
                acc_o[nt] = __builtin_amdgcn_mfma_f32_16x16x32_bf16(ap1, bv1, acc_o[nt], 0, 0, 0);
            }

            if (pf) {                          // transpose-write V(kt+1)
                const unsigned short* pa = (const unsigned short*)&va;
                const unsigned short* pb = (const unsigned short*)&vb;
                #pragma unroll
                for (int j = 0; j < 8; j++)
                    Vp[nxt][(vo + j) * 36 + vcol] = (unsigned)pa[j] | ((unsigned)pb[j] << 16);
            }
            __syncthreads();                   // drains async K(kt+1); Vp[nxt] visible
        }

        // epilogue: reduce l across the 16 lanes holding this row, normalize
        #pragma unroll
        for (int r = 0; r < 4; r++) {
            float rsum = lsum[r];
            #pragma unroll
            for (int off = 1; off < 16; off <<= 1)
                rsum += __shfl_xor(rsum, off, 16);
            float inv = 1.0f / rsum;
            int row = q0 + prow + r;
            #pragma unroll
            for (int nt = 0; nt < 4; nt++)
                Ows[(size_t)(b * S + row) * 1024 + h * 64 + nt * 16 + lro] =
                    f2bf(acc_o[nt][r] * inv);
        }
    }
}

// ---------------------------------------------------------------------------
extern "C" void kernel_launch(void* const* d_in, const int* in_sizes, int n_in,
                              void* d_out, int out_size, void* d_ws, size_t ws_size,
                              hipStream_t stream) {
    const float* x    = (const float*)d_in[0];   // (2, 2048, 1024)
    const int*   pos  = (const int*)d_in[1];     // (2048,)
    const float* Wqkv = (const float*)d_in[2];   // (3072, 1024)
    const float* Wo   = (const float*)d_in[3];   // (1024, 1024)
    float* out = (float*)d_out;                  // (2, 2048, 1024) fp32

    unsigned short* xb    = (unsigned short*)d_ws;            // 4096*1024
    unsigned short* Wqkvb = xb + (size_t)4096 * 1024;         // 3072*1024
    unsigned short* Wob   = Wqkvb + (size_t)3072 * 1024;      // 1024*1024
    unsigned short* qkvb  = Wob + (size_t)1024 * 1024;        // 4096*3072
    unsigned short* Owsb  = qkvb + (size_t)4096 * 3072;       // 4096*1024

    // 0) fp32 -> bf16 (single launch)
    cvt_all_bf16<<<8192, 256, 0, stream>>>(x, Wqkv, Wo, xb, Wqkvb, Wob);

    // 1) QKV projection (M=4096, N=3072, K=1024) + fused RoPE, double-buffered
    gemm_nt_mfma<4, 3, true, true><<<768, 256, 0, stream>>>(
        xb, Wqkvb, qkvb, pos, 3072, 1024);

    // 2) causal flash attention (paired q-tiles, pipelined, XCD-swizzled)
    flash_attn_mfma<<<dim3(16, 16, 2), 256, 0, stream>>>(qkvb, Owsb);

    // 3) output projection (M=4096, N=1024, K=1024), BM=64, double-buffered
    gemm_nt_mfma<2, 1, false, false><<<512, 256, 0, stream>>>(
        Owsb, Wob, out, nullptr, 1024, 1024);
}

// Round 8
// 184.915 us; speedup vs baseline: 1.0883x; 1.0599x over previous
//
#include <hip/hip_runtime.h>
#include <math.h>

typedef short short8 __attribute__((ext_vector_type(8)));
typedef float f32x4 __attribute__((ext_vector_type(4)));

typedef __attribute__((address_space(1))) const void* as1p;
typedef __attribute__((address_space(3))) void* as3p;

__device__ __forceinline__ unsigned short f2bf(float f) {
    unsigned int u = __float_as_uint(f);
    u += 0x7fffu + ((u >> 16) & 1u);          // RNE; inputs finite
    return (unsigned short)(u >> 16);
}
__device__ __forceinline__ float bf2f(unsigned int bits) {
    return __uint_as_float(bits << 16);
}

// ---------------------------------------------------------------------------
// fp32 -> bf16 conversion of x, W_qkv, W_o in one launch (4 elems/thread)
// ---------------------------------------------------------------------------
__global__ void cvt_all_bf16(const float* __restrict__ x,
                             const float* __restrict__ wqkv,
                             const float* __restrict__ wo,
                             unsigned short* __restrict__ xb,
                             unsigned short* __restrict__ wqkvb,
                             unsigned short* __restrict__ wob) {
    int i = blockIdx.x * blockDim.x + threadIdx.x;   // [0, 2097152)
    const float* src;
    unsigned short* dst;
    int off;
    if (i < 1048576)       { src = x;    dst = xb;    off = i; }
    else if (i < 1835008)  { src = wqkv; dst = wqkvb; off = i - 1048576; }
    else                   { src = wo;   dst = wob;   off = i - 1835008; }
    float4 v = ((const float4*)src)[off];
    ushort4 o = make_ushort4(f2bf(v.x), f2bf(v.y), f2bf(v.z), f2bf(v.w));
    ((ushort4*)dst)[off] = o;
}

// ---------------------------------------------------------------------------
// MFMA NT GEMM: C[m,n] = sum_k A[m,k]*B[n,k]. Block tile BM x 128 (BM=RF*32),
// BK=32, 4 waves (2x2), global_load_lds width-16 staging, 2-barrier K-loop
// (r7 showed explicit double-buffering REGRESSES this structure — m99/m100).
// LDS bank-conflict fix (r7: 3.1e6 conflict cycles): since global_load_lds
// pins LDS slot = base + lane*16, the XOR swizzle is applied by permuting the
// GLOBAL source chunk per lane (slot tid holds row tid>>2, logical chunk
// (tid&3)^((row>>1)&3)); fragment readers fetch physical chunk
// grp^((lro>>1)&3), which spreads each 8-lane phase across all 8 bank-quads.
// XCD-swizzled flat grid: xcd = L%8 owns NTX consecutive n-tiles (B panel
// L2-resident: qkv 786 KB, out-proj 256 KB < 4 MiB).
// DO_ROPE: fused RoPE on the fp32 accumulator before the bf16 store.
// ---------------------------------------------------------------------------
template <int RF, int NTX, bool BF16_OUT, bool DO_ROPE>
__global__ __launch_bounds__(256) void gemm_nt_mfma(
    const unsigned short* __restrict__ A, const unsigned short* __restrict__ B,
    void* __restrict__ Cv, const int* __restrict__ pos, int N, int K) {
    constexpr int BM = RF * 32;
    __shared__ unsigned short As[BM * 32];
    __shared__ unsigned short Bs[128 * 32];
    const int tid = threadIdx.x;
    const int wave = tid >> 6, lane = tid & 63;
    const int L = blockIdx.x;
    const int xcd = L & 7, idx = L >> 3;
    const int nt_ = xcd * NTX + idx % NTX;
    const int mt  = idx / NTX;
    const int m0 = mt * BM, n0 = nt_ << 7;
    const int wr = ((wave >> 1) & 1) * (RF * 16);
    const int wc = (wave & 1) << 6;

    // staging: slot tid -> row tid>>2, swizzled source chunk
    const int r0 = tid >> 2;
    const int ko = (((tid & 3) ^ ((r0 >> 1) & 3)) << 3);
    const unsigned short* Ap0 = A + (size_t)(m0 + r0) * K + ko;
    const unsigned short* Ap1 = A + (size_t)(m0 + (RF == 4 ? 64 : 0) + r0) * K + ko;
    const unsigned short* Bp0 = B + (size_t)(n0 + r0) * K + ko;
    const unsigned short* Bp1 = B + (size_t)(n0 + 64 + r0) * K + ko;

    f32x4 acc[RF][4] = {};
    const int lro = lane & 15;
    const int cs = ((lane >> 4) ^ ((lro >> 1) & 3)) << 3;  // physical chunk (shorts)

    for (int k0 = 0; k0 < K; k0 += 32) {
        __syncthreads();
        __builtin_amdgcn_global_load_lds((as1p)(Ap0 + k0), (as3p)(As + tid * 8), 16, 0, 0);
        if constexpr (RF == 4)
            __builtin_amdgcn_global_load_lds((as1p)(Ap1 + k0), (as3p)(As + (256 + tid) * 8), 16, 0, 0);
        __builtin_amdgcn_global_load_lds((as1p)(Bp0 + k0), (as3p)(Bs + tid * 8), 16, 0, 0);
        __builtin_amdgcn_global_load_lds((as1p)(Bp1 + k0), (as3p)(Bs + (256 + tid) * 8), 16, 0, 0);
        __syncthreads();

        short8 af[RF], bfr[4];
        #pragma unroll
        for (int i = 0; i < RF; i++) af[i] = *(const short8*)&As[(wr + i * 16 + lro) * 32 + cs];
        #pragma unroll
        for (int j = 0; j < 4; j++) bfr[j] = *(const short8*)&Bs[(wc + j * 16 + lro) * 32 + cs];
        #pragma unroll
        for (int i = 0; i < RF; i++)
            #pragma unroll
            for (int j = 0; j < 4; j++)
                acc[i][j] = __builtin_amdgcn_mfma_f32_16x16x32_bf16(af[i], bfr[j], acc[i][j], 0, 0, 0);
    }

    const int row_b = m0 + wr + ((lane >> 4) << 2);
    const int col_b = n0 + wc + lro;

    if constexpr (DO_ROPE) {
        const int sec = (n0 + wc) >> 10;           // 0=q, 1=k, 2=v
        if (sec < 2) {
            const float qs = (sec == 0) ? 0.18033688011112042f : 1.0f;  // 1/8*log2e
            const float sgn = (lane & 1) ? 1.0f : -1.0f;
            float ps[RF * 4];
            #pragma unroll
            for (int i = 0; i < RF; i++)
                #pragma unroll
                for (int r = 0; r < 4; r++)
                    ps[i * 4 + r] = (float)pos[(row_b + i * 16 + r) & 2047];
            #pragma unroll
            for (int j = 0; j < 4; j++) {
                // inv_freq / (2*pi):  10000^(-fi/32) * 0.159155,  fi = lro/2 + 8j
                float invf_rev = exp2f(-(float)((lro >> 1) + 8 * j) * 0.41524101186092029f)
                                 * 0.15915494309189535f;
                #pragma unroll
                for (int i = 0; i < RF; i++)
                    #pragma unroll
                    for (int r = 0; r < 4; r++) {
                        float rev = ps[i * 4 + r] * invf_rev;
                        rev -= floorf(rev);
                        float c = __builtin_amdgcn_cosf(rev) * qs;
                        float s = __builtin_amdgcn_sinf(rev) * (qs * sgn);
                        float mine = acc[i][j][r];
                        float partner = __shfl_xor(mine, 1, 64);
                        acc[i][j][r] = mine * c + partner * s;
                    }
            }
        }
    }

    #pragma unroll
    for (int i = 0; i < RF; i++)
        #pragma unroll
        for (int j = 0; j < 4; j++)
            #pragma unroll
            for (int r = 0; r < 4; r++) {
                size_t idx2 = (size_t)(row_b + i * 16 + r) * N + (col_b + j * 16);
                if constexpr (BF16_OUT) ((unsigned short*)Cv)[idx2] = f2bf(acc[i][j][r]);
                else ((float*)Cv)[idx2] = acc[i][j][r];
            }
}

// ---------------------------------------------------------------------------
// MFMA causal flash attention — paired-balanced (pp and 31-pp, 33 iters/block,
// 512 blocks), XCD-swizzled so all 16 blocks of a (b,h) share one XCD
// (K/V L2-resident, FETCH 122->12 MB). Q frags loaded directly
// global->registers. Softmax: scores pre-scaled (rope folded 1/8*log2e into
// q), no running max, denominator reduced once per phase. Per iter ONE
// barrier; K(kt+1) async global_load_lds; V(kt+1) register-prefetch +
// transpose at iter bottom. K LDS 16B-chunk XOR swizzle; V quad-swizzled;
// P stride 80.
// ---------------------------------------------------------------------------
__global__ __launch_bounds__(256) void flash_attn_mfma(
    const unsigned short* __restrict__ qkv, unsigned short* __restrict__ Ows) {
    const int S = 2048, D3 = 3072;
    const int L = blockIdx.x + (blockIdx.y << 4) + (blockIdx.z << 8);
    const int xcd = L & 7, t = L >> 3;
    const int pp = t & 15;
    const int g2 = xcd + ((t >> 4) << 3);      // (b,h) group, constant per XCD
    const int h = g2 & 15, b = g2 >> 4;
    const int tid = threadIdx.x, wave = tid >> 6, lane = tid & 63;
    const int lro = lane & 15, grp = lane >> 4;

    __shared__ __align__(16) unsigned short Ks[2][64 * 64];
    __shared__ __align__(16) unsigned int   Vp[2][64 * 36];
    __shared__ __align__(16) unsigned short Ps[64 * 80];

    // staging geometry (K): slot s -> row s>>3, swizzled source chunk
    const int sr = tid >> 3;
    const int sc = ((tid & 7) ^ (sr & 7)) << 3;
    // V transpose geometry
    const int kp = tid >> 3, vo = (tid & 7) << 3;
    const int vka = (kp >> 1) + ((kp & 1) << 5);
    const int vcol = (((kp >> 2) ^ (tid & 7)) << 2) | (kp & 3);

    // frag LDS offsets
    const int cq = grp ^ (lro & 7);
    int kof0[4], kof1[4], vbse[4], vq[4];
    #pragma unroll
    for (int nt = 0; nt < 4; nt++) {
        int R = nt * 16 + lro;
        kof0[nt] = R * 64 + cq * 8;
        kof1[nt] = R * 64 + (cq ^ 4) * 8;
        vbse[nt] = R * 36;
        vq[nt] = (grp ^ (R >> 3)) << 2;
    }
    const int apo = (wave * 16 + lro) * 80 + grp * 8;
    const int prow = wave * 16 + grp * 4;

    const unsigned short* kbg = qkv + (size_t)(b * S) * D3 + 1024 + h * 64;
    const unsigned short* vbg = qkv + (size_t)(b * S) * D3 + 2048 + h * 64;

    for (int ph = 0; ph < 2; ph++) {
        const int qt = ph ? 31 - pp : pp;
        const int q0 = qt << 6;
        const int nkt = qt + 1;

        __syncthreads();                       // prior phase fully done with LDS
        // Q frags direct from global (A-layout: row = wave*16+lro, k = grp*8(+32))
        const unsigned short* qrow =
            qkv + (size_t)(b * S + q0 + wave * 16 + lro) * D3 + h * 64 + grp * 8;
        short8 aq0 = *(const short8*)qrow;
        short8 aq1 = *(const short8*)(qrow + 32);

        // prime tile 0: K async, V reg->transpose
        __builtin_amdgcn_global_load_lds((as1p)(kbg + (size_t)sr * D3 + sc),
                                         (as3p)&Ks[0][tid * 8], 16, 0, 0);
        __builtin_amdgcn_global_load_lds((as1p)(kbg + (size_t)(sr + 32) * D3 + sc),
                                         (as3p)&Ks[0][(tid + 256) * 8], 16, 0, 0);
        {
            const unsigned short* vs = vbg + (size_t)vka * D3 + vo;
            uint4 va = *(const uint4*)vs;
            uint4 vb = *(const uint4*)(vs + (size_t)16 * D3);
            const unsigned short* pa = (const unsigned short*)&va;
            const unsigned short* pb = (const unsigned short*)&vb;
            #pragma unroll
            for (int j = 0; j < 8; j++)
                Vp[0][(vo + j) * 36 + vcol] = (unsigned)pa[j] | ((unsigned)pb[j] << 16);
        }
        __syncthreads();                       // K0 drained, V0 visible

        f32x4 acc_o[4] = {};
        float lsum[4] = {0.f, 0.f, 0.f, 0.f};

        for (int kt = 0; kt < nkt; kt++) {
            const int cur = kt & 1, nxt = cur ^ 1;
            const bool pf = (kt + 1 < nkt);
            uint4 va, vb;
            if (pf) {                          // prefetch kt+1 (overlaps compute)
                const unsigned short* kb1 = kbg + (size_t)((kt + 1) * 64) * D3;
                __builtin_amdgcn_global_load_lds((as1p)(kb1 + (size_t)sr * D3 + sc),
                                                 (as3p)&Ks[nxt][tid * 8], 16, 0, 0);
                __builtin_amdgcn_global_load_lds((as1p)(kb1 + (size_t)(sr + 32) * D3 + sc),
                                                 (as3p)&Ks[nxt][(tid + 256) * 8], 16, 0, 0);
                const unsigned short* vs = vbg + (size_t)((kt + 1) * 64 + vka) * D3 + vo;
                va = *(const uint4*)vs;
                vb = *(const uint4*)(vs + (size_t)16 * D3);
            }

            // S = Q K^T  (pre-scaled so p = exp2(s))
            f32x4 s[4] = {};
            #pragma unroll
            for (int nt = 0; nt < 4; nt++) {
                short8 bk0 = *(const short8*)&Ks[cur][kof0[nt]];
                short8 bk1 = *(const short8*)&Ks[cur][kof1[nt]];
                s[nt] = __builtin_amdgcn_mfma_f32_16x16x32_bf16(aq0, bk0, s[nt], 0, 0, 0);
                s[nt] = __builtin_amdgcn_mfma_f32_16x16x32_bf16(aq1, bk1, s[nt], 0, 0, 0);
            }

            const bool diag = (kt == nkt - 1);
            #pragma unroll
            for (int r = 0; r < 4; r++) {
                float v0 = s[0][r], v1 = s[1][r], v2 = s[2][r], v3 = s[3][r];
                if (diag) {
                    int rowl = prow + r;
                    if (lro > rowl) v0 = -1e30f;
                    if (16 + lro > rowl) v1 = -1e30f;
                    if (32 + lro > rowl) v2 = -1e30f;
                    if (48 + lro > rowl) v3 = -1e30f;
                }
                float p0 = __builtin_amdgcn_exp2f(v0);
                float p1 = __builtin_amdgcn_exp2f(v1);
                float p2 = __builtin_amdgcn_exp2f(v2);
                float p3 = __builtin_amdgcn_exp2f(v3);
                lsum[r] += (p0 + p1) + (p2 + p3);
                // cheap (round-half-up) bf16 pack
                unsigned u0 = __float_as_uint(p0) + 0x8000u;
                unsigned u1 = __float_as_uint(p1) + 0x8000u;
                unsigned u2 = __float_as_uint(p2) + 0x8000u;
                unsigned u3 = __float_as_uint(p3) + 0x8000u;
                uint2 w = make_uint2((u0 >> 16) | (u1 & 0xffff0000u),
                                     (u2 >> 16) | (u3 & 0xffff0000u));
                *(uint2*)&Ps[(prow + r) * 80 + lro * 4] = w;
            }

            // O += P V  (same-wave in-order LDS RAW on Ps)
            short8 ap0 = *(const short8*)&Ps[apo];
            short8 ap1 = *(const short8*)&Ps[apo + 32];
            #pragma unroll
            for (int nt = 0; nt < 4; nt++) {
                short8 bv0 = *(const short8*)&Vp[cur][vbse[nt] + vq[nt]];
                short8 bv1 = *(const short8*)&Vp[cur][vbse[nt] + (vq[nt] ^ 16)];
                acc_o[nt] = __builtin_amdgcn_mfma_f32_16x16x32_bf16(ap0, bv0, acc_o[nt], 0, 0, 0);
                acc_o[nt] = __builtin_amdgcn_mfma_f32_16x16x32_bf16(ap1, bv1, acc_o[nt], 0, 0, 0);
            }

            if (pf) {                          // transpose-write V(kt+1)
                const unsigned short* pa = (const unsigned short*)&va;
                const unsigned short* pb = (const unsigned short*)&vb;
                #pragma unroll
                for (int j = 0; j < 8; j++)
                    Vp[nxt][(vo + j) * 36 + vcol] = (unsigned)pa[j] | ((unsigned)pb[j] << 16);
            }
            __syncthreads();                   // drains async K(kt+1); Vp[nxt] visible
        }

        // epilogue: reduce l across the 16 lanes holding this row, normalize
        #pragma unroll
        for (int r = 0; r < 4; r++) {
            float rsum = lsum[r];
            #pragma unroll
            for (int off = 1; off < 16; off <<= 1)
                rsum += __shfl_xor(rsum, off, 16);
            float inv = 1.0f / rsum;
            int row = q0 + prow + r;
            #pragma unroll
            for (int nt = 0; nt < 4; nt++)
                Ows[(size_t)(b * S + row) * 1024 + h * 64 + nt * 16 + lro] =
                    f2bf(acc_o[nt][r] * inv);
        }
    }
}

// ---------------------------------------------------------------------------
extern "C" void kernel_launch(void* const* d_in, const int* in_sizes, int n_in,
                              void* d_out, int out_size, void* d_ws, size_t ws_size,
                              hipStream_t stream) {
    const float* x    = (const float*)d_in[0];   // (2, 2048, 1024)
    const int*   pos  = (const int*)d_in[1];     // (2048,)
    const float* Wqkv = (const float*)d_in[2];   // (3072, 1024)
    const float* Wo   = (const float*)d_in[3];   // (1024, 1024)
    float* out = (float*)d_out;                  // (2, 2048, 1024) fp32

    unsigned short* xb    = (unsigned short*)d_ws;            // 4096*1024
    unsigned short* Wqkvb = xb + (size_t)4096 * 1024;         // 3072*1024
    unsigned short* Wob   = Wqkvb + (size_t)3072 * 1024;      // 1024*1024
    unsigned short* qkvb  = Wob + (size_t)1024 * 1024;        // 4096*3072
    unsigned short* Owsb  = qkvb + (size_t)4096 * 3072;       // 4096*1024

    // 0) fp32 -> bf16 (single launch)
    cvt_all_bf16<<<8192, 256, 0, stream>>>(x, Wqkv, Wo, xb, Wqkvb, Wob);

    // 1) QKV projection (M=4096, N=3072, K=1024) + fused RoPE, swizzled LDS
    gemm_nt_mfma<4, 3, true, true><<<768, 256, 0, stream>>>(
        xb, Wqkvb, qkvb, pos, 3072, 1024);

    // 2) causal flash attention (paired q-tiles, pipelined, XCD-swizzled)
    flash_attn_mfma<<<dim3(16, 16, 2), 256, 0, stream>>>(qkvb, Owsb);

    // 3) output projection (M=4096, N=1024, K=1024), BM=64, swizzled LDS
    gemm_nt_mfma<2, 1, false, false><<<512, 256, 0, stream>>>(
        Owsb, Wob, out, nullptr, 1024, 1024);
}